// Round 10
// baseline (769.694 us; speedup 1.0000x reference)
//
#include <hip/hip_runtime.h>
#include <cstdint>
#include <cstddef>

#define HID 128

typedef __bf16 bf16x8 __attribute__((ext_vector_type(8)));
typedef float f32x4 __attribute__((ext_vector_type(4)));

// ---------- helpers ----------
__device__ __forceinline__ float bf2f(uint32_t u) {
    union { uint32_t i; float f; } x; x.i = u << 16; return x.f;
}
__device__ __forceinline__ float bflo(uint32_t p) { return bf2f(p & 0xffffu); }
__device__ __forceinline__ float bfhi(uint32_t p) { return bf2f(p >> 16); }
__device__ __forceinline__ float bfs(const uint16_t* p) { return bf2f((uint32_t)*p); }
__device__ __forceinline__ uint16_t f2bf(float f) {
    union { float f; uint32_t i; } x; x.f = f;
    uint32_t u = x.i;
    return (uint16_t)((u + 0x7fffu + ((u >> 16) & 1u)) >> 16);   // RNE
}
__device__ __forceinline__ uint32_t pack2(float a, float b) {
    return (uint32_t)f2bf(a) | ((uint32_t)f2bf(b) << 16);
}
__device__ __forceinline__ float lrelu_f(float v) { return v > 0.f ? v : 0.01f * v; }
__device__ __forceinline__ bf16x8 ldfrag(const uint16_t* p) {
    union { uint4 u; bf16x8 b; } c;
    c.u = *(const uint4*)p;
    return c.b;
}

// ---------- ws-too-small sentinel ----------
__global__ __launch_bounds__(256) void sentinel_kernel(float* out, int n) {
    int i = blockIdx.x * 256 + threadIdx.x;
    if (i < n) out[i] = 65536.0f;
}

// ---------- dtype probes ----------
__global__ void detect_e_kernel(const int* __restrict__ ei, int* __restrict__ flagE) {
    int lane = threadIdx.x;                       // 64 threads
    int w = ei[2 * lane + 1];
    unsigned long long b = __ballot(w != 0);
    if (lane == 0) flagE[0] = (b == 0ULL) ? 1 : 0;   // 1 = int64
}
__global__ void detect_f_kernel(const uint32_t* __restrict__ x, int* __restrict__ flagF) {
    int lane = threadIdx.x;                       // 64 threads
    uint32_t e = (x[lane] >> 7) & 0xFFu;
    unsigned long long b = __ballot(e >= 64u && e <= 144u);
    if (lane == 0) flagF[0] = (b == ~0ULL) ? 0 : 1;  // 1 = fp32, 0 = bf16
}

// ---------- weight canonicalize: W[n][k] -> bf16 copy (same layout) ----------
struct WArgs {
    const void* src[8];
    uint16_t* dst[8];
    int nrows[8];
};
__global__ __launch_bounds__(256) void convert_w(WArgs a, const int* __restrict__ flagF) {
    int mat = blockIdx.x >> 6;                    // 64 blocks per matrix
    int idx = ((blockIdx.x & 63) << 8) + threadIdx.x;
    if (idx < a.nrows[mat] * HID) {
        a.dst[mat][idx] = flagF[0] ? f2bf(((const float*)a.src[mat])[idx])
                                   : ((const uint16_t*)a.src[mat])[idx];
    }
}

// ---------- param vectors -> canonical fp32 buffer ----------
struct ParamArgs {
    const void* src[14];
    int off[14];
    int cnt[14];
};
__global__ __launch_bounds__(128) void convert_params(ParamArgs pa, float* __restrict__ params,
                                                      const int* __restrict__ flagF) {
    int b = blockIdx.x, t = threadIdx.x;          // 14 blocks x 128
    if (t < pa.cnt[b]) {
        float v = flagF[0] ? ((const float*)pa.src[b])[t]
                           : bfs(&((const uint16_t*)pa.src[b])[t]);
        params[pa.off[b] + t] = v;
    }
}

// ---------- x -> canonical bf16 feature buffer ----------
__global__ __launch_bounds__(256) void convert_x(const void* __restrict__ x,
                                                 uint32_t* __restrict__ dst,
                                                 const int* __restrict__ flagF, int total2) {
    int i = blockIdx.x * 256 + threadIdx.x;
    if (i >= total2) return;
    if (flagF[0]) {
        float2 v = ((const float2*)x)[i];
        dst[i] = pack2(v.x, v.y);
    } else {
        dst[i] = ((const uint32_t*)x)[i];
    }
}

// ---------- CSR build: block-local LDS binning over 1024-node coarse buckets ----------
#define EPB 2048                                  // edges per fill/hist block

__global__ __launch_bounds__(256) void bucket_hist(const int* __restrict__ ei,
                                                   const int* __restrict__ flagE,
                                                   int* __restrict__ bcnt, int E, int NBC) {
    __shared__ int cnt[1024];
    int tid = threadIdx.x;
    for (int b = tid; b < NBC; b += 256) cnt[b] = 0;
    __syncthreads();
    int e0 = blockIdx.x * EPB, e1 = min(e0 + EPB, E);
    int isl = flagE[0];
    for (int i = e0 + tid; i < e1; i += 256) {
        int d = isl ? ei[2 * (E + i)] : ei[E + i];
        atomicAdd(&cnt[d >> 10], 1);
    }
    __syncthreads();
    for (int b = tid; b < NBC; b += 256)
        if (cnt[b]) atomicAdd(&bcnt[b], cnt[b]);
}
__global__ __launch_bounds__(1024) void bucket_scan(const int* __restrict__ bcnt,
                                                    int* __restrict__ bstart,
                                                    int* __restrict__ gcur, int NBC, int E) {
    __shared__ int sm[1024];
    int tid = threadIdx.x;
    int v = (tid < NBC) ? bcnt[tid] : 0;
    sm[tid] = v;
    __syncthreads();
    for (int off = 1; off < 1024; off <<= 1) {
        int t = (tid >= off) ? sm[tid - off] : 0;
        __syncthreads();
        sm[tid] += t;
        __syncthreads();
    }
    int ex = sm[tid] - v;
    if (tid < NBC) { bstart[tid] = ex; gcur[tid] = ex; }
    if (tid == 0) bstart[NBC] = E;
}
__global__ __launch_bounds__(256) void bucket_fill(const int* __restrict__ ei,
                                                   const int* __restrict__ flagE,
                                                   int* __restrict__ gcur,
                                                   uint2* __restrict__ bins, int E, int NBC) {
    __shared__ int cnt[1024];
    __shared__ int res[1024];
    int tid = threadIdx.x;
    for (int b = tid; b < NBC; b += 256) cnt[b] = 0;
    __syncthreads();
    int e0 = blockIdx.x * EPB, e1 = min(e0 + EPB, E);
    int isl = flagE[0];
    for (int i = e0 + tid; i < e1; i += 256) {
        int d = isl ? ei[2 * (E + i)] : ei[E + i];
        atomicAdd(&cnt[d >> 10], 1);
    }
    __syncthreads();
    for (int b = tid; b < NBC; b += 256) {
        res[b] = cnt[b] ? atomicAdd(&gcur[b], cnt[b]) : 0;
        cnt[b] = 0;                               // becomes local cursor
    }
    __syncthreads();
    for (int i = e0 + tid; i < e1; i += 256) {
        int s = isl ? ei[2 * i] : ei[i];
        int d = isl ? ei[2 * (E + i)] : ei[E + i];
        int b = d >> 10;
        int pos = res[b] + atomicAdd(&cnt[b], 1);
        bins[pos] = make_uint2((uint32_t)s, (uint32_t)d);
    }
}
__global__ __launch_bounds__(256) void csr_build(const uint2* __restrict__ bins,
                                                 const int* __restrict__ bstart,
                                                 int* __restrict__ rowptr,
                                                 int* __restrict__ csr, int M, int E) {
    int b = blockIdx.x;
    int node0 = b << 10;
    int nn = min(1024, M - node0);
    int s = bstart[b], e = bstart[b + 1];
    __shared__ int cnt[1024];
    __shared__ int ofs[1024];
    int tid = threadIdx.x;
    for (int j = tid; j < 1024; j += 256) cnt[j] = 0;
    __syncthreads();
    for (int i = s + tid; i < e; i += 256)
        atomicAdd(&cnt[bins[i].y & 1023], 1);
    __syncthreads();
    if (tid == 0) {
        int run = s;
        for (int j = 0; j < nn; ++j) { ofs[j] = run; run += cnt[j]; }
    }
    __syncthreads();
    for (int j = tid; j < nn; j += 256) rowptr[node0 + j] = ofs[j];
    if (b == 0 && tid == 0) rowptr[M] = E;
    for (int j = tid; j < 1024; j += 256) cnt[j] = 0;   // reuse as cursors
    __syncthreads();
    for (int i = s + tid; i < e; i += 256) {
        uint2 pr = bins[i];
        int d = pr.y & 1023;
        int pos = ofs[d] + atomicAdd(&cnt[d], 1);
        csr[pos] = (int)pr.x;
    }
}

// ---------- max aggregation: 4 nodes/wave (16 lanes x uint4), 8-edge unroll ----------
__global__ __launch_bounds__(256) void gather_kernel(const uint4* __restrict__ cur,
                                                     const int* __restrict__ rowptr,
                                                     const int* __restrict__ csr,
                                                     uint4* __restrict__ agg, int M) {
    int gid = blockIdx.x * 256 + threadIdx.x;
    int node = gid >> 4;
    int sl = threadIdx.x & 15;                    // 16-lane subgroup, 16 B each
    if (node >= M) return;
    int b = rowptr[node], e = rowptr[node + 1];
    float m[8];
#pragma unroll
    for (int j = 0; j < 8; ++j) m[j] = -INFINITY;
    int i = b;
    for (; i + 8 <= e; i += 8) {                  // 8 loads in flight per lane
        uint4 u[8];
#pragma unroll
        for (int t = 0; t < 8; ++t) u[t] = cur[(size_t)csr[i + t] * 16 + sl];
#pragma unroll
        for (int t = 0; t < 8; ++t) {
            uint32_t w[4] = {u[t].x, u[t].y, u[t].z, u[t].w};
#pragma unroll
            for (int j = 0; j < 4; ++j) {
                m[2 * j]     = fmaxf(m[2 * j],     bflo(w[j]));
                m[2 * j + 1] = fmaxf(m[2 * j + 1], bfhi(w[j]));
            }
        }
    }
    for (; i + 4 <= e; i += 4) {
        uint4 u[4];
#pragma unroll
        for (int t = 0; t < 4; ++t) u[t] = cur[(size_t)csr[i + t] * 16 + sl];
#pragma unroll
        for (int t = 0; t < 4; ++t) {
            uint32_t w[4] = {u[t].x, u[t].y, u[t].z, u[t].w};
#pragma unroll
            for (int j = 0; j < 4; ++j) {
                m[2 * j]     = fmaxf(m[2 * j],     bflo(w[j]));
                m[2 * j + 1] = fmaxf(m[2 * j + 1], bfhi(w[j]));
            }
        }
    }
    for (; i < e; ++i) {
        uint4 u0 = cur[(size_t)csr[i] * 16 + sl];
        uint32_t w0[4] = {u0.x, u0.y, u0.z, u0.w};
#pragma unroll
        for (int j = 0; j < 4; ++j) {
            m[2 * j]     = fmaxf(m[2 * j],     bflo(w0[j]));
            m[2 * j + 1] = fmaxf(m[2 * j + 1], bfhi(w0[j]));
        }
    }
    if (b == e) {
#pragma unroll
        for (int j = 0; j < 8; ++j) m[j] = 0.f;   // no neighbors -> 0 (isfinite rule)
    }
    uint4 o;
    o.x = pack2(m[0], m[1]); o.y = pack2(m[2], m[3]);
    o.z = pack2(m[4], m[5]); o.w = pack2(m[6], m[7]);
    agg[(size_t)node * 16 + sl] = o;
}

// ---------- MFMA GEMM: out[M][N] = sum_s A_s @ W_s^T + bias ----------
// STATS: per-block column sum/sumsq of raw z -> pblk[block][256] (NO atomics —
// r6's 400k-device-atomic storm avoided; cs/cq live only in the epilogue so the
// main-loop VGPR peak and the (256,3) occupancy are unchanged).
template<int N, int NSRC, bool FC2, bool STATS>
__global__ __launch_bounds__(256, 3) void gemm_mfma(
    const uint16_t* __restrict__ A0, const uint16_t* __restrict__ W0,
    const uint16_t* __restrict__ A1, const uint16_t* __restrict__ W1,
    const float* __restrict__ bias, void* __restrict__ out_, int M,
    const float* __restrict__ fc2w, float* __restrict__ pblk)
{
    constexpr int LDT = 72;                       // row stride in uint16 (144 B)
    constexpr int WAVES_N = N / 64;               // 2 (N=128) or 1 (N=64)
    constexpr int WAVES_M = 4 / WAVES_N;          // 2 or 4
    constexpr int MT = 8 / WAVES_M;               // m-tiles/wave: 4 or 2
    constexpr int NT = 4;                         // n-tiles/wave (64 cols)
    constexpr int NW = N / 32;                    // W staging passes (4 or 2)
    constexpr int CHUNKS = 2 * NSRC;              // BK=64 chunks
    __shared__ uint16_t LX[128 * LDT];            // X tile [row][k64]
    __shared__ uint16_t LW[N * LDT];              // W tile [n][k64]
    const int tid = threadIdx.x;
    const int wave = tid >> 6, lane = tid & 63;
    const int l15 = lane & 15, lkg = lane >> 4;   // k-group 0..3
    const int wn = (wave % WAVES_N) * 64;
    const int wm = (wave / WAVES_N) * (128 / WAVES_M);
    const int row0 = blockIdx.x * 128;
    const int srow = tid >> 3;                    // staging row 0..31 (+32*pass)
    const int sko = (tid & 7) * 8;                // staging k offset, uint16 units

    f32x4 acc[NT][MT];
#pragma unroll
    for (int nt = 0; nt < NT; ++nt)
#pragma unroll
        for (int mt = 0; mt < MT; ++mt) {
            f32x4 z4 = {0.f, 0.f, 0.f, 0.f};
            acc[nt][mt] = z4;
        }

    const uint16_t* Asrc[2] = {A0, NSRC > 1 ? A1 : A0};
    const uint16_t* Wsrc[2] = {W0, NSRC > 1 ? W1 : W0};

    uint4 rx[4], rw[NW];
#pragma unroll
    for (int it = 0; it < 4; ++it) {
        int gr = row0 + srow + it * 32;
        uint4 v = make_uint4(0, 0, 0, 0);
        if (gr < M) v = *(const uint4*)(Asrc[0] + (size_t)gr * HID + sko);
        rx[it] = v;
    }
#pragma unroll
    for (int it = 0; it < NW; ++it)
        rw[it] = *(const uint4*)(Wsrc[0] + (size_t)(srow + it * 32) * HID + sko);

#pragma unroll 1
    for (int c = 0; c < CHUNKS; ++c) {
        __syncthreads();
#pragma unroll
        for (int it = 0; it < 4; ++it)
            *(uint4*)&LX[(srow + it * 32) * LDT + sko] = rx[it];
#pragma unroll
        for (int it = 0; it < NW; ++it)
            *(uint4*)&LW[(srow + it * 32) * LDT + sko] = rw[it];
        __syncthreads();
        if (c + 1 < CHUNKS) {                     // issue next chunk's loads now
            int nc = c + 1, src = nc >> 1, kc = nc & 1;
            const uint16_t* Ag = Asrc[src];
#pragma unroll
            for (int it = 0; it < 4; ++it) {
                int gr = row0 + srow + it * 32;
                uint4 v = make_uint4(0, 0, 0, 0);
                if (gr < M) v = *(const uint4*)(Ag + (size_t)gr * HID + kc * 64 + sko);
                rx[it] = v;
            }
            const uint16_t* Wg = Wsrc[src];
#pragma unroll
            for (int it = 0; it < NW; ++it)
                rw[it] = *(const uint4*)(Wg + (size_t)(srow + it * 32) * HID + kc * 64 + sko);
        }
#pragma unroll
        for (int ks = 0; ks < 2; ++ks) {
            bf16x8 xf[MT], wf[NT];
#pragma unroll
            for (int mt = 0; mt < MT; ++mt)
                xf[mt] = ldfrag(&LX[(wm + mt * 16 + l15) * LDT + ks * 32 + lkg * 8]);
#pragma unroll
            for (int nt = 0; nt < NT; ++nt)
                wf[nt] = ldfrag(&LW[(wn + nt * 16 + l15) * LDT + ks * 32 + lkg * 8]);
#pragma unroll
            for (int nt = 0; nt < NT; ++nt)
#pragma unroll
                for (int mt = 0; mt < MT; ++mt)
                    acc[nt][mt] = __builtin_amdgcn_mfma_f32_16x16x32_bf16(
                        wf[nt], xf[mt], acc[nt][mt], 0, 0, 0);
        }
    }

    if constexpr (FC2) {
        float rowdot[MT];
#pragma unroll
        for (int mt = 0; mt < MT; ++mt) rowdot[mt] = 0.f;
#pragma unroll
        for (int nt = 0; nt < NT; ++nt) {
            int n0 = wn + nt * 16 + lkg * 4;
            float b4[4] = {bias[n0], bias[n0 + 1], bias[n0 + 2], bias[n0 + 3]};
            float w4[4] = {fc2w[n0], fc2w[n0 + 1], fc2w[n0 + 2], fc2w[n0 + 3]};
#pragma unroll
            for (int mt = 0; mt < MT; ++mt) {
                f32x4 f = acc[nt][mt];
#pragma unroll
                for (int j = 0; j < 4; ++j)
                    rowdot[mt] = fmaf(lrelu_f(f[j] + b4[j]), w4[j], rowdot[mt]);
            }
        }
        float b2 = fc2w[64];
#pragma unroll
        for (int mt = 0; mt < MT; ++mt) {
            float v = rowdot[mt];
            v += __shfl_xor(v, 16, 64);
            v += __shfl_xor(v, 32, 64);
            int m = row0 + wm + mt * 16 + l15;
            if (lkg == 0 && m < M) ((float*)out_)[m] = v + b2;
        }
    } else {
        float cs[16], cq[16];
        if constexpr (STATS) {
#pragma unroll
            for (int v = 0; v < 16; ++v) { cs[v] = 0.f; cq[v] = 0.f; }
        }
#pragma unroll
        for (int nt = 0; nt < NT; ++nt) {
            int n0 = wn + nt * 16 + lkg * 4;
            float b0 = bias[n0], b1 = bias[n0 + 1], b2 = bias[n0 + 2], b3 = bias[n0 + 3];
#pragma unroll
            for (int mt = 0; mt < MT; ++mt) {
                int m = row0 + wm + mt * 16 + l15;
                if (m < M) {
                    f32x4 f = acc[nt][mt];
                    float o0 = f[0] + b0, o1 = f[1] + b1, o2 = f[2] + b2, o3 = f[3] + b3;
                    if constexpr (STATS) {
                        cs[nt * 4 + 0] += o0; cq[nt * 4 + 0] = fmaf(o0, o0, cq[nt * 4 + 0]);
                        cs[nt * 4 + 1] += o1; cq[nt * 4 + 1] = fmaf(o1, o1, cq[nt * 4 + 1]);
                        cs[nt * 4 + 2] += o2; cq[nt * 4 + 2] = fmaf(o2, o2, cq[nt * 4 + 2]);
                        cs[nt * 4 + 3] += o3; cq[nt * 4 + 3] = fmaf(o3, o3, cq[nt * 4 + 3]);
                    }
                    ushort4 ov;
                    ov.x = f2bf(o0); ov.y = f2bf(o1);
                    ov.z = f2bf(o2); ov.w = f2bf(o3);
                    *(ushort4*)((uint16_t*)out_ + (size_t)m * N + n0) = ov;
                }
            }
        }
        if constexpr (STATS) {                    // N==128 path only
            // reduce across the 16 row-lanes (l15), then cross-wave via LDS
#pragma unroll
            for (int v = 0; v < 16; ++v) {
                float a = cs[v], q = cq[v];
                a += __shfl_xor(a, 1, 64); q += __shfl_xor(q, 1, 64);
                a += __shfl_xor(a, 2, 64); q += __shfl_xor(q, 2, 64);
                a += __shfl_xor(a, 4, 64); q += __shfl_xor(q, 4, 64);
                a += __shfl_xor(a, 8, 64); q += __shfl_xor(q, 8, 64);
                cs[v] = a; cq[v] = q;
            }
            float* sred = (float*)LX;             // 2 mgroups x 256 floats = 2 KB
            __syncthreads();                      // LX free for reuse
            if (l15 == 0) {
                int g = wave >> 1;                // m-group (WAVES_N=2)
#pragma unroll
                for (int v = 0; v < 16; ++v) {
                    int col = wn + (v >> 2) * 16 + lkg * 4 + (v & 3);
                    sred[g * 256 + col] = cs[v];
                    sred[g * 256 + 128 + col] = cq[v];
                }
            }
            __syncthreads();
            pblk[(size_t)blockIdx.x * 256 + tid] = sred[tid] + sred[256 + tid];
        }
    }
}

// ---------- reduce per-block BN partials + finalize scale/shift ----------
// grid 8 x 256; block owns 16 columns; pblk[b][c]=sum, pblk[b][128+c]=sumsq
__global__ __launch_bounds__(256) void reduce_finalize(const float* __restrict__ pblk,
                                                       int nblk, float* __restrict__ stats,
                                                       const float* __restrict__ g,
                                                       const float* __restrict__ be, int M) {
    __shared__ float sm[2][256];
    int tid = threadIdx.x;
    int col = blockIdx.x * 16 + (tid & 15);
    int chunk = tid >> 4;                         // 0..15
    float s = 0.f, q = 0.f;
    for (int b = chunk; b < nblk; b += 16) {
        s += pblk[(size_t)b * 256 + col];
        q += pblk[(size_t)b * 256 + 128 + col];
    }
    sm[0][tid] = s; sm[1][tid] = q;
    __syncthreads();
    if (tid < 16) {
        float s2 = 0.f, q2 = 0.f;
        for (int j = 0; j < 16; ++j) { s2 += sm[0][tid + 16 * j]; q2 += sm[1][tid + 16 * j]; }
        int c = blockIdx.x * 16 + tid;
        float mean = s2 / (float)M;
        float var = q2 / (float)M - mean * mean;
        float sc = g[c] * rsqrtf(var + 1e-5f);
        stats[c] = sc;
        stats[128 + c] = be[c] - mean * sc;
    }
}

// ---------- batch norm apply ----------
__global__ __launch_bounds__(256) void bn_apply(uint32_t* __restrict__ z,
                                                const float* __restrict__ stats, int total2) {
    int i = blockIdx.x * 256 + threadIdx.x;
    if (i >= total2) return;
    int cc = (i & 63) * 2;
    uint32_t u = z[i];
    float a = lrelu_f(fmaf(bflo(u), stats[cc], stats[128 + cc]));
    float b = lrelu_f(fmaf(bfhi(u), stats[cc + 1], stats[129 + cc]));
    z[i] = pack2(a, b);
}
// layer-3 variant with fused residual add: z = lrelu(bn(z)) + h0
__global__ __launch_bounds__(256) void bn_apply_res(uint32_t* __restrict__ z,
                                                    const uint32_t* __restrict__ h0,
                                                    const float* __restrict__ stats, int total2) {
    int i = blockIdx.x * 256 + threadIdx.x;
    if (i >= total2) return;
    int cc = (i & 63) * 2;
    uint32_t u = z[i], r = h0[i];
    float a = lrelu_f(fmaf(bflo(u), stats[cc], stats[128 + cc])) + bflo(r);
    float b = lrelu_f(fmaf(bfhi(u), stats[cc + 1], stats[129 + cc])) + bfhi(r);
    z[i] = pack2(a, b);
}

// ---------- launch ----------
extern "C" void kernel_launch(void* const* d_in, const int* in_sizes, int n_in,
                              void* d_out, int out_size, void* d_ws, size_t ws_size,
                              hipStream_t stream) {
    const void* x = d_in[0];                               // [M][128] bf16 or fp32
    const int* ei = (const int*)d_in[1];                   // int32 or int64 [2][E]
    const int M = in_sizes[0] / HID;                       // 100000
    const int E = in_sizes[1] / 2;                         // 1600000
    const int NBC = (M + 1023) >> 10;                      // 1024-node buckets (<=1024)
    const int gemm_grid = (M + 127) / 128;

    // workspace layout — ~85 MB (P doubles as 12.8 MB bin scratch pre-layer1)
    const size_t FEAT = (size_t)M * HID * 2;               // 25.6 MB per bf16 buffer
    char* p = (char*)d_ws;
    uint16_t* H0 = (uint16_t*)p; p += FEAT;                // residual, persists
    uint16_t* P  = (uint16_t*)p; p += FEAT;                // ALSO: edge bins (uint2[E])
    uint16_t* Q  = (uint16_t*)p; p += FEAT;
    uint16_t* WT = (uint16_t*)p; p += 8 * 16384 * 2;       // 8 bf16 weight slots [n][k]
    float* params = (float*)p; p += 8192;                  // canonical fp32 params
    int* rowptr  = (int*)p; p += ((size_t)M + 32) * 4;
    int* csr     = (int*)p; p += (size_t)E * 4;
    int* bcnt    = (int*)p; p += 1024 * 4;                 // coarse bucket counts
    int* bstart  = (int*)p; p += 1056 * 4;                 // bucket region bases
    int* gcur    = (int*)p; p += 1024 * 4;                 // bucket fill cursors
    float* stats = (float*)p; p += 3 * 256 * 4;            // 3 BN scale/shift slots
    float* pblk  = (float*)p; p += (size_t)gemm_grid * 256 * 4;  // BN partials (~800 KB)
    int* flagE   = (int*)p; p += 128;
    int* flagF   = (int*)p; p += 128;

    const size_t needed = (size_t)(p - (char*)d_ws);
    if (needed > ws_size) {                                // diagnostic sentinel
        sentinel_kernel<<<(out_size + 255) / 256, 256, 0, stream>>>(
            (float*)d_out, out_size);
        return;
    }

    uint16_t* wt[8];
    for (int i = 0; i < 8; ++i) wt[i] = WT + (size_t)i * 16384;

    // 0) dtype probes
    detect_e_kernel<<<1, 64, 0, stream>>>(ei, flagE);
    detect_f_kernel<<<1, 64, 0, stream>>>((const uint32_t*)x, flagF);

    // 1) canonicalize weights + params + x
    WArgs wa;
    const int widx[8] = {2, 4, 6, 7, 9, 10, 12, 19};       // W_in,Wl1,Wr1,Wl2,Wr2,Wl3,Wr3,Wfc1
    for (int i = 0; i < 8; ++i) {
        wa.src[i] = d_in[widx[i]];
        wa.dst[i] = wt[i];
        wa.nrows[i] = (i == 7) ? 64 : 128;
    }
    convert_w<<<512, 256, 0, stream>>>(wa, flagF);

    ParamArgs pa;
    const int pidx[14] = {3, 5, 8, 11, 13, 15, 17, 14, 16, 18, 20, 21, 22, 22};
    const int poff[14] = {0, 128, 256, 384, 512, 640, 768, 896, 1024, 1152, 1280, 1344, 1408, 1409};
    const int pcnt[14] = {128, 128, 128, 128, 128, 128, 128, 128, 128, 128, 64, 64, 1, 0};
    for (int i = 0; i < 14; ++i) { pa.src[i] = d_in[pidx[i]]; pa.off[i] = poff[i]; pa.cnt[i] = pcnt[i]; }
    convert_params<<<14, 128, 0, stream>>>(pa, params, flagF);
    // map: 0 b_in | 128/256/384 b_l1..3 | 512/640/768 g1..3 | 896/1024/1152 be1..3
    //      1280 b_fc1[64] | 1344 W_fc2[64] | 1408 b_fc2

    const int total2 = M * (HID / 2);
    const int ew_grid = (total2 + 255) / 256;
    convert_x<<<ew_grid, 256, 0, stream>>>(x, (uint32_t*)Q, flagF, total2);

    // 2) CSR build: coarse hist -> scan -> block-local binned fill -> per-bucket CSR
    hipMemsetAsync(bcnt, 0, 1024 * sizeof(int), stream);
    const int fgrid = (E + EPB - 1) / EPB;
    bucket_hist<<<fgrid, 256, 0, stream>>>(ei, flagE, bcnt, E, NBC);
    bucket_scan<<<1, 1024, 0, stream>>>(bcnt, bstart, gcur, NBC, E);
    bucket_fill<<<fgrid, 256, 0, stream>>>(ei, flagE, gcur, (uint2*)P, E, NBC);
    csr_build<<<NBC, 256, 0, stream>>>((const uint2*)P, bstart, rowptr, csr, M, E);

    const int gather_grid = (M + 15) / 16;                 // 4 nodes per wave

    // 3) h0 = x @ W_in^T + b_in  (residual, bf16)
    gemm_mfma<128, 1, false, false><<<gemm_grid, 256, 0, stream>>>(
        Q, wt[0], nullptr, nullptr, params + 0, H0, M, nullptr, nullptr);

    // 4) three SAGE layers (gather -> gemm w/ fused BN partial-stats -> reduce -> apply)
    uint16_t* wtl[3] = {wt[1], wt[3], wt[5]};
    uint16_t* wtr[3] = {wt[2], wt[4], wt[6]};
    uint16_t* cur = H0;
    uint16_t* dstb[3] = {P, Q, P};
    for (int l = 0; l < 3; ++l) {
        uint16_t* z = dstb[l];
        float* sl = stats + 256 * l;
        gather_kernel<<<gather_grid, 256, 0, stream>>>(
            (const uint4*)cur, rowptr, csr, (uint4*)z, M);
        gemm_mfma<128, 2, false, true><<<gemm_grid, 256, 0, stream>>>(
            z, wtl[l], cur, wtr[l], params + 128 + l * 128, z, M, nullptr, pblk);
        reduce_finalize<<<8, 256, 0, stream>>>(pblk, gemm_grid, sl,
                                               params + 512 + l * 128,
                                               params + 896 + l * 128, M);
        if (l < 2)
            bn_apply<<<ew_grid, 256, 0, stream>>>((uint32_t*)z, sl, total2);
        else
            bn_apply_res<<<ew_grid, 256, 0, stream>>>((uint32_t*)z, (const uint32_t*)H0,
                                                      sl, total2);
        cur = z;
    }

    // 5) fused fc1(+lrelu)+fc2 -> fp32 d_out
    gemm_mfma<64, 1, true, false><<<gemm_grid, 256, 0, stream>>>(
        P, wt[7], nullptr, nullptr, params + 1280, (float*)d_out, M,
        params + 1344, nullptr);
}

// Round 11
// 727.460 us; speedup vs baseline: 1.0581x; 1.0581x over previous
//
#include <hip/hip_runtime.h>
#include <cstdint>
#include <cstddef>

#define HID 128

typedef __bf16 bf16x8 __attribute__((ext_vector_type(8)));
typedef float f32x4 __attribute__((ext_vector_type(4)));

// ---------- helpers ----------
__device__ __forceinline__ float bf2f(uint32_t u) {
    union { uint32_t i; float f; } x; x.i = u << 16; return x.f;
}
__device__ __forceinline__ float bflo(uint32_t p) { return bf2f(p & 0xffffu); }
__device__ __forceinline__ float bfhi(uint32_t p) { return bf2f(p >> 16); }
__device__ __forceinline__ float bfs(const uint16_t* p) { return bf2f((uint32_t)*p); }
__device__ __forceinline__ uint16_t f2bf(float f) {
    union { float f; uint32_t i; } x; x.f = f;
    uint32_t u = x.i;
    return (uint16_t)((u + 0x7fffu + ((u >> 16) & 1u)) >> 16);   // RNE
}
__device__ __forceinline__ uint32_t pack2(float a, float b) {
    return (uint32_t)f2bf(a) | ((uint32_t)f2bf(b) << 16);
}
__device__ __forceinline__ float lrelu_f(float v) { return v > 0.f ? v : 0.01f * v; }
__device__ __forceinline__ bf16x8 ldfrag(const uint16_t* p) {
    union { uint4 u; bf16x8 b; } c;
    c.u = *(const uint4*)p;
    return c.b;
}

// ---------- ws-too-small sentinel ----------
__global__ __launch_bounds__(256) void sentinel_kernel(float* out, int n) {
    int i = blockIdx.x * 256 + threadIdx.x;
    if (i < n) out[i] = 65536.0f;
}

// ---------- dtype probes ----------
__global__ void detect_e_kernel(const int* __restrict__ ei, int* __restrict__ flagE) {
    int lane = threadIdx.x;                       // 64 threads
    int w = ei[2 * lane + 1];
    unsigned long long b = __ballot(w != 0);
    if (lane == 0) flagE[0] = (b == 0ULL) ? 1 : 0;   // 1 = int64
}
__global__ void detect_f_kernel(const uint32_t* __restrict__ x, int* __restrict__ flagF) {
    int lane = threadIdx.x;                       // 64 threads
    uint32_t e = (x[lane] >> 7) & 0xFFu;
    unsigned long long b = __ballot(e >= 64u && e <= 144u);
    if (lane == 0) flagF[0] = (b == ~0ULL) ? 0 : 1;  // 1 = fp32, 0 = bf16
}

// ---------- weight canonicalize: W[n][k] -> bf16 copy (same layout) ----------
struct WArgs {
    const void* src[8];
    uint16_t* dst[8];
    int nrows[8];
};
__global__ __launch_bounds__(256) void convert_w(WArgs a, const int* __restrict__ flagF) {
    int mat = blockIdx.x >> 6;                    // 64 blocks per matrix
    int idx = ((blockIdx.x & 63) << 8) + threadIdx.x;
    if (idx < a.nrows[mat] * HID) {
        a.dst[mat][idx] = flagF[0] ? f2bf(((const float*)a.src[mat])[idx])
                                   : ((const uint16_t*)a.src[mat])[idx];
    }
}

// ---------- param vectors -> canonical fp32 buffer ----------
struct ParamArgs {
    const void* src[14];
    int off[14];
    int cnt[14];
};
__global__ __launch_bounds__(128) void convert_params(ParamArgs pa, float* __restrict__ params,
                                                      const int* __restrict__ flagF) {
    int b = blockIdx.x, t = threadIdx.x;          // 14 blocks x 128
    if (t < pa.cnt[b]) {
        float v = flagF[0] ? ((const float*)pa.src[b])[t]
                           : bfs(&((const uint16_t*)pa.src[b])[t]);
        params[pa.off[b] + t] = v;
    }
}

// ---------- x -> canonical bf16 feature buffer ----------
__global__ __launch_bounds__(256) void convert_x(const void* __restrict__ x,
                                                 uint32_t* __restrict__ dst,
                                                 const int* __restrict__ flagF, int total2) {
    int i = blockIdx.x * 256 + threadIdx.x;
    if (i >= total2) return;
    if (flagF[0]) {
        float2 v = ((const float2*)x)[i];
        dst[i] = pack2(v.x, v.y);
    } else {
        dst[i] = ((const uint32_t*)x)[i];
    }
}

// ---------- CSR build: block-local LDS binning over 1024-node coarse buckets ----------
#define EPB 2048                                  // edges per fill/hist block

__global__ __launch_bounds__(256) void bucket_hist(const int* __restrict__ ei,
                                                   const int* __restrict__ flagE,
                                                   int* __restrict__ bcnt, int E, int NBC) {
    __shared__ int cnt[1024];
    int tid = threadIdx.x;
    for (int b = tid; b < NBC; b += 256) cnt[b] = 0;
    __syncthreads();
    int e0 = blockIdx.x * EPB, e1 = min(e0 + EPB, E);
    int isl = flagE[0];
    for (int i = e0 + tid; i < e1; i += 256) {
        int d = isl ? ei[2 * (E + i)] : ei[E + i];
        atomicAdd(&cnt[d >> 10], 1);
    }
    __syncthreads();
    for (int b = tid; b < NBC; b += 256)
        if (cnt[b]) atomicAdd(&bcnt[b], cnt[b]);
}
__global__ __launch_bounds__(1024) void bucket_scan(const int* __restrict__ bcnt,
                                                    int* __restrict__ bstart,
                                                    int* __restrict__ gcur, int NBC, int E) {
    __shared__ int sm[1024];
    int tid = threadIdx.x;
    int v = (tid < NBC) ? bcnt[tid] : 0;
    sm[tid] = v;
    __syncthreads();
    for (int off = 1; off < 1024; off <<= 1) {
        int t = (tid >= off) ? sm[tid - off] : 0;
        __syncthreads();
        sm[tid] += t;
        __syncthreads();
    }
    int ex = sm[tid] - v;
    if (tid < NBC) { bstart[tid] = ex; gcur[tid] = ex; }
    if (tid == 0) bstart[NBC] = E;
}
__global__ __launch_bounds__(256) void bucket_fill(const int* __restrict__ ei,
                                                   const int* __restrict__ flagE,
                                                   int* __restrict__ gcur,
                                                   uint2* __restrict__ bins, int E, int NBC) {
    __shared__ int cnt[1024];
    __shared__ int res[1024];
    int tid = threadIdx.x;
    for (int b = tid; b < NBC; b += 256) cnt[b] = 0;
    __syncthreads();
    int e0 = blockIdx.x * EPB, e1 = min(e0 + EPB, E);
    int isl = flagE[0];
    for (int i = e0 + tid; i < e1; i += 256) {
        int d = isl ? ei[2 * (E + i)] : ei[E + i];
        atomicAdd(&cnt[d >> 10], 1);
    }
    __syncthreads();
    for (int b = tid; b < NBC; b += 256) {
        res[b] = cnt[b] ? atomicAdd(&gcur[b], cnt[b]) : 0;
        cnt[b] = 0;                               // becomes local cursor
    }
    __syncthreads();
    for (int i = e0 + tid; i < e1; i += 256) {
        int s = isl ? ei[2 * i] : ei[i];
        int d = isl ? ei[2 * (E + i)] : ei[E + i];
        int b = d >> 10;
        int pos = res[b] + atomicAdd(&cnt[b], 1);
        bins[pos] = make_uint2((uint32_t)s, (uint32_t)d);
    }
}
__global__ __launch_bounds__(256) void csr_build(const uint2* __restrict__ bins,
                                                 const int* __restrict__ bstart,
                                                 int* __restrict__ rowptr,
                                                 int* __restrict__ csr, int M, int E) {
    int b = blockIdx.x;
    int node0 = b << 10;
    int nn = min(1024, M - node0);
    int s = bstart[b], e = bstart[b + 1];
    __shared__ int cnt[1024];
    __shared__ int ofs[1024];
    int tid = threadIdx.x;
    for (int j = tid; j < 1024; j += 256) cnt[j] = 0;
    __syncthreads();
    for (int i = s + tid; i < e; i += 256)
        atomicAdd(&cnt[bins[i].y & 1023], 1);
    __syncthreads();
    if (tid == 0) {
        int run = s;
        for (int j = 0; j < nn; ++j) { ofs[j] = run; run += cnt[j]; }
    }
    __syncthreads();
    for (int j = tid; j < nn; j += 256) rowptr[node0 + j] = ofs[j];
    if (b == 0 && tid == 0) rowptr[M] = E;
    for (int j = tid; j < 1024; j += 256) cnt[j] = 0;   // reuse as cursors
    __syncthreads();
    for (int i = s + tid; i < e; i += 256) {
        uint2 pr = bins[i];
        int d = pr.y & 1023;
        int pos = ofs[d] + atomicAdd(&cnt[d], 1);
        csr[pos] = (int)pr.x;
    }
}

// ---------- max aggregation: 4 nodes/wave (16 lanes x uint4), 8-edge unroll ----------
__global__ __launch_bounds__(256) void gather_kernel(const uint4* __restrict__ cur,
                                                     const int* __restrict__ rowptr,
                                                     const int* __restrict__ csr,
                                                     uint4* __restrict__ agg, int M) {
    int gid = blockIdx.x * 256 + threadIdx.x;
    int node = gid >> 4;
    int sl = threadIdx.x & 15;                    // 16-lane subgroup, 16 B each
    if (node >= M) return;
    int b = rowptr[node], e = rowptr[node + 1];
    float m[8];
#pragma unroll
    for (int j = 0; j < 8; ++j) m[j] = -INFINITY;
    int i = b;
    for (; i + 8 <= e; i += 8) {                  // 8 loads in flight per lane
        uint4 u[8];
#pragma unroll
        for (int t = 0; t < 8; ++t) u[t] = cur[(size_t)csr[i + t] * 16 + sl];
#pragma unroll
        for (int t = 0; t < 8; ++t) {
            uint32_t w[4] = {u[t].x, u[t].y, u[t].z, u[t].w};
#pragma unroll
            for (int j = 0; j < 4; ++j) {
                m[2 * j]     = fmaxf(m[2 * j],     bflo(w[j]));
                m[2 * j + 1] = fmaxf(m[2 * j + 1], bfhi(w[j]));
            }
        }
    }
    for (; i + 4 <= e; i += 4) {
        uint4 u[4];
#pragma unroll
        for (int t = 0; t < 4; ++t) u[t] = cur[(size_t)csr[i + t] * 16 + sl];
#pragma unroll
        for (int t = 0; t < 4; ++t) {
            uint32_t w[4] = {u[t].x, u[t].y, u[t].z, u[t].w};
#pragma unroll
            for (int j = 0; j < 4; ++j) {
                m[2 * j]     = fmaxf(m[2 * j],     bflo(w[j]));
                m[2 * j + 1] = fmaxf(m[2 * j + 1], bfhi(w[j]));
            }
        }
    }
    for (; i < e; ++i) {
        uint4 u0 = cur[(size_t)csr[i] * 16 + sl];
        uint32_t w0[4] = {u0.x, u0.y, u0.z, u0.w};
#pragma unroll
        for (int j = 0; j < 4; ++j) {
            m[2 * j]     = fmaxf(m[2 * j],     bflo(w0[j]));
            m[2 * j + 1] = fmaxf(m[2 * j + 1], bfhi(w0[j]));
        }
    }
    if (b == e) {
#pragma unroll
        for (int j = 0; j < 8; ++j) m[j] = 0.f;   // no neighbors -> 0 (isfinite rule)
    }
    uint4 o;
    o.x = pack2(m[0], m[1]); o.y = pack2(m[2], m[3]);
    o.z = pack2(m[4], m[5]); o.w = pack2(m[6], m[7]);
    agg[(size_t)node * 16 + sl] = o;
}

// ---------- MFMA GEMM: out[M][N] = sum_s A_s @ W_s^T + bias (r8/r9 proven) ----------
// NOTE: BN-stats fusion attempted twice (r6 atomics, r10 spill) — both regressed.
// The (256,3) budget has no register headroom for a stats epilogue. Do not re-add.
template<int N, int NSRC, bool FC2>
__global__ __launch_bounds__(256, 3) void gemm_mfma(
    const uint16_t* __restrict__ A0, const uint16_t* __restrict__ W0,
    const uint16_t* __restrict__ A1, const uint16_t* __restrict__ W1,
    const float* __restrict__ bias, void* __restrict__ out_, int M,
    const float* __restrict__ fc2w)
{
    constexpr int LDT = 72;                       // row stride in uint16 (144 B)
    constexpr int WAVES_N = N / 64;               // 2 (N=128) or 1 (N=64)
    constexpr int WAVES_M = 4 / WAVES_N;          // 2 or 4
    constexpr int MT = 8 / WAVES_M;               // m-tiles/wave: 4 or 2
    constexpr int NT = 4;                         // n-tiles/wave (64 cols)
    constexpr int NW = N / 32;                    // W staging passes (4 or 2)
    constexpr int CHUNKS = 2 * NSRC;              // BK=64 chunks
    __shared__ uint16_t LX[128 * LDT];            // X tile [row][k64]
    __shared__ uint16_t LW[N * LDT];              // W tile [n][k64]
    const int tid = threadIdx.x;
    const int wave = tid >> 6, lane = tid & 63;
    const int l15 = lane & 15, lkg = lane >> 4;   // k-group 0..3
    const int wn = (wave % WAVES_N) * 64;
    const int wm = (wave / WAVES_N) * (128 / WAVES_M);
    const int row0 = blockIdx.x * 128;
    const int srow = tid >> 3;                    // staging row 0..31 (+32*pass)
    const int sko = (tid & 7) * 8;                // staging k offset, uint16 units

    f32x4 acc[NT][MT];
#pragma unroll
    for (int nt = 0; nt < NT; ++nt)
#pragma unroll
        for (int mt = 0; mt < MT; ++mt) {
            f32x4 z4 = {0.f, 0.f, 0.f, 0.f};
            acc[nt][mt] = z4;
        }

    const uint16_t* Asrc[2] = {A0, NSRC > 1 ? A1 : A0};
    const uint16_t* Wsrc[2] = {W0, NSRC > 1 ? W1 : W0};

    uint4 rx[4], rw[NW];
#pragma unroll
    for (int it = 0; it < 4; ++it) {
        int gr = row0 + srow + it * 32;
        uint4 v = make_uint4(0, 0, 0, 0);
        if (gr < M) v = *(const uint4*)(Asrc[0] + (size_t)gr * HID + sko);
        rx[it] = v;
    }
#pragma unroll
    for (int it = 0; it < NW; ++it)
        rw[it] = *(const uint4*)(Wsrc[0] + (size_t)(srow + it * 32) * HID + sko);

#pragma unroll 1
    for (int c = 0; c < CHUNKS; ++c) {
        __syncthreads();
#pragma unroll
        for (int it = 0; it < 4; ++it)
            *(uint4*)&LX[(srow + it * 32) * LDT + sko] = rx[it];
#pragma unroll
        for (int it = 0; it < NW; ++it)
            *(uint4*)&LW[(srow + it * 32) * LDT + sko] = rw[it];
        __syncthreads();
        if (c + 1 < CHUNKS) {                     // issue next chunk's loads now
            int nc = c + 1, src = nc >> 1, kc = nc & 1;
            const uint16_t* Ag = Asrc[src];
#pragma unroll
            for (int it = 0; it < 4; ++it) {
                int gr = row0 + srow + it * 32;
                uint4 v = make_uint4(0, 0, 0, 0);
                if (gr < M) v = *(const uint4*)(Ag + (size_t)gr * HID + kc * 64 + sko);
                rx[it] = v;
            }
            const uint16_t* Wg = Wsrc[src];
#pragma unroll
            for (int it = 0; it < NW; ++it)
                rw[it] = *(const uint4*)(Wg + (size_t)(srow + it * 32) * HID + kc * 64 + sko);
        }
#pragma unroll
        for (int ks = 0; ks < 2; ++ks) {
            bf16x8 xf[MT], wf[NT];
#pragma unroll
            for (int mt = 0; mt < MT; ++mt)
                xf[mt] = ldfrag(&LX[(wm + mt * 16 + l15) * LDT + ks * 32 + lkg * 8]);
#pragma unroll
            for (int nt = 0; nt < NT; ++nt)
                wf[nt] = ldfrag(&LW[(wn + nt * 16 + l15) * LDT + ks * 32 + lkg * 8]);
#pragma unroll
            for (int nt = 0; nt < NT; ++nt)
#pragma unroll
                for (int mt = 0; mt < MT; ++mt)
                    acc[nt][mt] = __builtin_amdgcn_mfma_f32_16x16x32_bf16(
                        wf[nt], xf[mt], acc[nt][mt], 0, 0, 0);
        }
    }

    if constexpr (FC2) {
        float rowdot[MT];
#pragma unroll
        for (int mt = 0; mt < MT; ++mt) rowdot[mt] = 0.f;
#pragma unroll
        for (int nt = 0; nt < NT; ++nt) {
            int n0 = wn + nt * 16 + lkg * 4;
            float b4[4] = {bias[n0], bias[n0 + 1], bias[n0 + 2], bias[n0 + 3]};
            float w4[4] = {fc2w[n0], fc2w[n0 + 1], fc2w[n0 + 2], fc2w[n0 + 3]};
#pragma unroll
            for (int mt = 0; mt < MT; ++mt) {
                f32x4 f = acc[nt][mt];
#pragma unroll
                for (int j = 0; j < 4; ++j)
                    rowdot[mt] = fmaf(lrelu_f(f[j] + b4[j]), w4[j], rowdot[mt]);
            }
        }
        float b2 = fc2w[64];
#pragma unroll
        for (int mt = 0; mt < MT; ++mt) {
            float v = rowdot[mt];
            v += __shfl_xor(v, 16, 64);
            v += __shfl_xor(v, 32, 64);
            int m = row0 + wm + mt * 16 + l15;
            if (lkg == 0 && m < M) ((float*)out_)[m] = v + b2;
        }
    } else {
#pragma unroll
        for (int nt = 0; nt < NT; ++nt) {
            int n0 = wn + nt * 16 + lkg * 4;
            float b0 = bias[n0], b1 = bias[n0 + 1], b2 = bias[n0 + 2], b3 = bias[n0 + 3];
#pragma unroll
            for (int mt = 0; mt < MT; ++mt) {
                int m = row0 + wm + mt * 16 + l15;
                if (m < M) {
                    f32x4 f = acc[nt][mt];
                    ushort4 ov;
                    ov.x = f2bf(f[0] + b0); ov.y = f2bf(f[1] + b1);
                    ov.z = f2bf(f[2] + b2); ov.w = f2bf(f[3] + b3);
                    *(ushort4*)((uint16_t*)out_ + (size_t)m * N + n0) = ov;
                }
            }
        }
    }
}

// ---------- batch norm (round-5 proven structure) ----------
__global__ __launch_bounds__(256) void bn_stats(const uint32_t* __restrict__ z,
                                                float* __restrict__ stats, int M, int rpb) {
    __shared__ float4 red[256];
    int c2 = threadIdx.x & 63;                    // uint32 column (2 features)
    int part = threadIdx.x >> 6;                  // 0..3
    int s0 = blockIdx.x * rpb, e0 = min(s0 + rpb, M);
    float sl = 0.f, s2l = 0.f, sh = 0.f, s2h = 0.f;
    for (int r = s0 + part; r < e0; r += 4) {
        uint32_t u = z[(size_t)r * 64 + c2];
        float a = bflo(u), b = bfhi(u);
        sl += a; s2l = fmaf(a, a, s2l);
        sh += b; s2h = fmaf(b, b, s2h);
    }
    red[threadIdx.x] = make_float4(sl, s2l, sh, s2h);
    __syncthreads();
    if (threadIdx.x < 64) {
        float4 v = red[threadIdx.x];
        float4 v1 = red[threadIdx.x + 64], v2 = red[threadIdx.x + 128], v3 = red[threadIdx.x + 192];
        v.x += v1.x + v2.x + v3.x; v.y += v1.y + v2.y + v3.y;
        v.z += v1.z + v2.z + v3.z; v.w += v1.w + v2.w + v3.w;
        int cc = c2 * 2;
        atomicAdd(&stats[cc], v.x);
        atomicAdd(&stats[128 + cc], v.y);
        atomicAdd(&stats[cc + 1], v.z);
        atomicAdd(&stats[129 + cc], v.w);
    }
}
__global__ void bn_finalize(float* stats, const float* __restrict__ g,
                            const float* __restrict__ be, int M) {
    int c = threadIdx.x;                          // 128 threads
    float mean = stats[c] / (float)M;
    float var = stats[128 + c] / (float)M - mean * mean;
    float sc = g[c] * rsqrtf(var + 1e-5f);
    stats[c] = sc;
    stats[128 + c] = be[c] - mean * sc;
}
__global__ __launch_bounds__(256) void bn_apply(uint32_t* __restrict__ z,
                                                const float* __restrict__ stats, int total2) {
    int i = blockIdx.x * 256 + threadIdx.x;
    if (i >= total2) return;
    int cc = (i & 63) * 2;
    uint32_t u = z[i];
    float a = lrelu_f(fmaf(bflo(u), stats[cc], stats[128 + cc]));
    float b = lrelu_f(fmaf(bfhi(u), stats[cc + 1], stats[129 + cc]));
    z[i] = pack2(a, b);
}
// layer-3 variant with fused residual add: z = lrelu(bn(z)) + h0
__global__ __launch_bounds__(256) void bn_apply_res(uint32_t* __restrict__ z,
                                                    const uint32_t* __restrict__ h0,
                                                    const float* __restrict__ stats, int total2) {
    int i = blockIdx.x * 256 + threadIdx.x;
    if (i >= total2) return;
    int cc = (i & 63) * 2;
    uint32_t u = z[i], r = h0[i];
    float a = lrelu_f(fmaf(bflo(u), stats[cc], stats[128 + cc])) + bflo(r);
    float b = lrelu_f(fmaf(bfhi(u), stats[cc + 1], stats[129 + cc])) + bfhi(r);
    z[i] = pack2(a, b);
}

// ---------- launch ----------
extern "C" void kernel_launch(void* const* d_in, const int* in_sizes, int n_in,
                              void* d_out, int out_size, void* d_ws, size_t ws_size,
                              hipStream_t stream) {
    const void* x = d_in[0];                               // [M][128] bf16 or fp32
    const int* ei = (const int*)d_in[1];                   // int32 or int64 [2][E]
    const int M = in_sizes[0] / HID;                       // 100000
    const int E = in_sizes[1] / 2;                         // 1600000
    const int NBC = (M + 1023) >> 10;                      // 1024-node buckets (<=1024)
    const int gemm_grid = (M + 127) / 128;

    // workspace layout — ~84 MB (P doubles as 12.8 MB bin scratch pre-layer1)
    const size_t FEAT = (size_t)M * HID * 2;               // 25.6 MB per bf16 buffer
    char* p = (char*)d_ws;
    uint16_t* H0 = (uint16_t*)p; p += FEAT;                // residual, persists
    uint16_t* P  = (uint16_t*)p; p += FEAT;                // ALSO: edge bins (uint2[E])
    uint16_t* Q  = (uint16_t*)p; p += FEAT;
    uint16_t* WT = (uint16_t*)p; p += 8 * 16384 * 2;       // 8 bf16 weight slots [n][k]
    float* params = (float*)p; p += 8192;                  // canonical fp32 params
    int* rowptr  = (int*)p; p += ((size_t)M + 32) * 4;
    int* csr     = (int*)p; p += (size_t)E * 4;
    int* bcnt    = (int*)p; p += 1024 * 4;                 // coarse bucket counts
    int* bstart  = (int*)p; p += 1056 * 4;                 // bucket region bases
    int* gcur    = (int*)p; p += 1024 * 4;                 // bucket fill cursors
    float* stats = (float*)p; p += 3 * 256 * 4;            // 3 BN stat slots
    int* flagE   = (int*)p; p += 128;
    int* flagF   = (int*)p; p += 128;

    const size_t needed = (size_t)(p - (char*)d_ws);
    if (needed > ws_size) {                                // diagnostic sentinel
        sentinel_kernel<<<(out_size + 255) / 256, 256, 0, stream>>>(
            (float*)d_out, out_size);
        return;
    }

    uint16_t* wt[8];
    for (int i = 0; i < 8; ++i) wt[i] = WT + (size_t)i * 16384;

    // 0) dtype probes
    detect_e_kernel<<<1, 64, 0, stream>>>(ei, flagE);
    detect_f_kernel<<<1, 64, 0, stream>>>((const uint32_t*)x, flagF);

    // 1) canonicalize weights + params + x
    WArgs wa;
    const int widx[8] = {2, 4, 6, 7, 9, 10, 12, 19};       // W_in,Wl1,Wr1,Wl2,Wr2,Wl3,Wr3,Wfc1
    for (int i = 0; i < 8; ++i) {
        wa.src[i] = d_in[widx[i]];
        wa.dst[i] = wt[i];
        wa.nrows[i] = (i == 7) ? 64 : 128;
    }
    convert_w<<<512, 256, 0, stream>>>(wa, flagF);

    ParamArgs pa;
    const int pidx[14] = {3, 5, 8, 11, 13, 15, 17, 14, 16, 18, 20, 21, 22, 22};
    const int poff[14] = {0, 128, 256, 384, 512, 640, 768, 896, 1024, 1152, 1280, 1344, 1408, 1409};
    const int pcnt[14] = {128, 128, 128, 128, 128, 128, 128, 128, 128, 128, 64, 64, 1, 0};
    for (int i = 0; i < 14; ++i) { pa.src[i] = d_in[pidx[i]]; pa.off[i] = poff[i]; pa.cnt[i] = pcnt[i]; }
    convert_params<<<14, 128, 0, stream>>>(pa, params, flagF);
    // map: 0 b_in | 128/256/384 b_l1..3 | 512/640/768 g1..3 | 896/1024/1152 be1..3
    //      1280 b_fc1[64] | 1344 W_fc2[64] | 1408 b_fc2

    const int total2 = M * (HID / 2);
    const int ew_grid = (total2 + 255) / 256;
    convert_x<<<ew_grid, 256, 0, stream>>>(x, (uint32_t*)Q, flagF, total2);

    // 2) CSR build: coarse hist -> scan -> block-local binned fill -> per-bucket CSR
    hipMemsetAsync(bcnt, 0, 1024 * sizeof(int), stream);
    hipMemsetAsync(stats, 0, 3 * 256 * sizeof(float), stream);
    const int fgrid = (E + EPB - 1) / EPB;
    bucket_hist<<<fgrid, 256, 0, stream>>>(ei, flagE, bcnt, E, NBC);
    bucket_scan<<<1, 1024, 0, stream>>>(bcnt, bstart, gcur, NBC, E);
    bucket_fill<<<fgrid, 256, 0, stream>>>(ei, flagE, gcur, (uint2*)P, E, NBC);
    csr_build<<<NBC, 256, 0, stream>>>((const uint2*)P, bstart, rowptr, csr, M, E);

    const int gather_grid = (M + 15) / 16;                 // 4 nodes per wave
    const int rpb = (M + 255) / 256;

    // 3) h0 = x @ W_in^T + b_in  (residual, bf16)
    gemm_mfma<128, 1, false><<<gemm_grid, 256, 0, stream>>>(
        Q, wt[0], nullptr, nullptr, params + 0, H0, M, nullptr);

    // 4) three SAGE layers (gather -> gemm in-place -> bn_stats -> finalize -> apply)
    uint16_t* wtl[3] = {wt[1], wt[3], wt[5]};
    uint16_t* wtr[3] = {wt[2], wt[4], wt[6]};
    uint16_t* cur = H0;
    uint16_t* dstb[3] = {P, Q, P};
    for (int l = 0; l < 3; ++l) {
        uint16_t* z = dstb[l];
        float* sl = stats + 256 * l;
        gather_kernel<<<gather_grid, 256, 0, stream>>>(
            (const uint4*)cur, rowptr, csr, (uint4*)z, M);
        gemm_mfma<128, 2, false><<<gemm_grid, 256, 0, stream>>>(
            z, wtl[l], cur, wtr[l], params + 128 + l * 128, z, M, nullptr);
        bn_stats<<<256, 256, 0, stream>>>((const uint32_t*)z, sl, M, rpb);
        bn_finalize<<<1, 128, 0, stream>>>(sl, params + 512 + l * 128,
                                           params + 896 + l * 128, M);
        if (l < 2)
            bn_apply<<<ew_grid, 256, 0, stream>>>((uint32_t*)z, sl, total2);
        else
            bn_apply_res<<<ew_grid, 256, 0, stream>>>((uint32_t*)z, (const uint32_t*)H0,
                                                      sl, total2);
        cur = z;
    }

    // 5) fused fc1(+lrelu)+fc2 -> fp32 d_out
    gemm_mfma<64, 1, true><<<gemm_grid, 256, 0, stream>>>(
        P, wt[7], nullptr, nullptr, params + 1280, (float*)d_out, M, params + 1344);
}

// Round 12
// 719.683 us; speedup vs baseline: 1.0695x; 1.0108x over previous
//
#include <hip/hip_runtime.h>
#include <cstdint>
#include <cstddef>

#define HID 128

typedef __bf16 bf16x8 __attribute__((ext_vector_type(8)));
typedef float f32x4 __attribute__((ext_vector_type(4)));

// ---------- helpers ----------
__device__ __forceinline__ float bf2f(uint32_t u) {
    union { uint32_t i; float f; } x; x.i = u << 16; return x.f;
}
__device__ __forceinline__ float bflo(uint32_t p) { return bf2f(p & 0xffffu); }
__device__ __forceinline__ float bfhi(uint32_t p) { return bf2f(p >> 16); }
__device__ __forceinline__ float bfs(const uint16_t* p) { return bf2f((uint32_t)*p); }
__device__ __forceinline__ uint16_t f2bf(float f) {
    union { float f; uint32_t i; } x; x.f = f;
    uint32_t u = x.i;
    return (uint16_t)((u + 0x7fffu + ((u >> 16) & 1u)) >> 16);   // RNE
}
__device__ __forceinline__ uint32_t pack2(float a, float b) {
    return (uint32_t)f2bf(a) | ((uint32_t)f2bf(b) << 16);
}
__device__ __forceinline__ float lrelu_f(float v) { return v > 0.f ? v : 0.01f * v; }
__device__ __forceinline__ bf16x8 ldfrag(const uint16_t* p) {
    union { uint4 u; bf16x8 b; } c;
    c.u = *(const uint4*)p;
    return c.b;
}

// ---------- ws-too-small sentinel ----------
__global__ __launch_bounds__(256) void sentinel_kernel(float* out, int n) {
    int i = blockIdx.x * 256 + threadIdx.x;
    if (i < n) out[i] = 65536.0f;
}

// ---------- dtype probes ----------
__global__ void detect_e_kernel(const int* __restrict__ ei, int* __restrict__ flagE) {
    int lane = threadIdx.x;                       // 64 threads
    int w = ei[2 * lane + 1];
    unsigned long long b = __ballot(w != 0);
    if (lane == 0) flagE[0] = (b == 0ULL) ? 1 : 0;   // 1 = int64
}
__global__ void detect_f_kernel(const uint32_t* __restrict__ x, int* __restrict__ flagF) {
    int lane = threadIdx.x;                       // 64 threads
    uint32_t e = (x[lane] >> 7) & 0xFFu;
    unsigned long long b = __ballot(e >= 64u && e <= 144u);
    if (lane == 0) flagF[0] = (b == ~0ULL) ? 0 : 1;  // 1 = fp32, 0 = bf16
}

// ---------- weight canonicalize: W[n][k] -> bf16 copy (same layout) ----------
struct WArgs {
    const void* src[8];
    uint16_t* dst[8];
    int nrows[8];
};
__global__ __launch_bounds__(256) void convert_w(WArgs a, const int* __restrict__ flagF) {
    int mat = blockIdx.x >> 6;                    // 64 blocks per matrix
    int idx = ((blockIdx.x & 63) << 8) + threadIdx.x;
    if (idx < a.nrows[mat] * HID) {
        a.dst[mat][idx] = flagF[0] ? f2bf(((const float*)a.src[mat])[idx])
                                   : ((const uint16_t*)a.src[mat])[idx];
    }
}

// ---------- param vectors -> canonical fp32 buffer ----------
struct ParamArgs {
    const void* src[14];
    int off[14];
    int cnt[14];
};
__global__ __launch_bounds__(128) void convert_params(ParamArgs pa, float* __restrict__ params,
                                                      const int* __restrict__ flagF) {
    int b = blockIdx.x, t = threadIdx.x;          // 14 blocks x 128
    if (t < pa.cnt[b]) {
        float v = flagF[0] ? ((const float*)pa.src[b])[t]
                           : bfs(&((const uint16_t*)pa.src[b])[t]);
        params[pa.off[b] + t] = v;
    }
}

// ---------- x -> canonical bf16 feature buffer ----------
__global__ __launch_bounds__(256) void convert_x(const void* __restrict__ x,
                                                 uint32_t* __restrict__ dst,
                                                 const int* __restrict__ flagF, int total2) {
    int i = blockIdx.x * 256 + threadIdx.x;
    if (i >= total2) return;
    if (flagF[0]) {
        float2 v = ((const float2*)x)[i];
        dst[i] = pack2(v.x, v.y);
    } else {
        dst[i] = ((const uint32_t*)x)[i];
    }
}

// ---------- CSR build: block-local LDS binning over 1024-node coarse buckets ----------
#define EPB 2048                                  // edges per fill/hist block

__global__ __launch_bounds__(256) void bucket_hist(const int* __restrict__ ei,
                                                   const int* __restrict__ flagE,
                                                   int* __restrict__ bcnt, int E, int NBC) {
    __shared__ int cnt[1024];
    int tid = threadIdx.x;
    for (int b = tid; b < NBC; b += 256) cnt[b] = 0;
    __syncthreads();
    int e0 = blockIdx.x * EPB, e1 = min(e0 + EPB, E);
    int isl = flagE[0];
    for (int i = e0 + tid; i < e1; i += 256) {
        int d = isl ? ei[2 * (E + i)] : ei[E + i];
        atomicAdd(&cnt[d >> 10], 1);
    }
    __syncthreads();
    for (int b = tid; b < NBC; b += 256)
        if (cnt[b]) atomicAdd(&bcnt[b], cnt[b]);
}
__global__ __launch_bounds__(1024) void bucket_scan(const int* __restrict__ bcnt,
                                                    int* __restrict__ bstart,
                                                    int* __restrict__ gcur, int NBC, int E) {
    __shared__ int sm[1024];
    int tid = threadIdx.x;
    int v = (tid < NBC) ? bcnt[tid] : 0;
    sm[tid] = v;
    __syncthreads();
    for (int off = 1; off < 1024; off <<= 1) {
        int t = (tid >= off) ? sm[tid - off] : 0;
        __syncthreads();
        sm[tid] += t;
        __syncthreads();
    }
    int ex = sm[tid] - v;
    if (tid < NBC) { bstart[tid] = ex; gcur[tid] = ex; }
    if (tid == 0) bstart[NBC] = E;
}
__global__ __launch_bounds__(256) void bucket_fill(const int* __restrict__ ei,
                                                   const int* __restrict__ flagE,
                                                   int* __restrict__ gcur,
                                                   uint2* __restrict__ bins, int E, int NBC) {
    __shared__ int cnt[1024];
    __shared__ int res[1024];
    int tid = threadIdx.x;
    for (int b = tid; b < NBC; b += 256) cnt[b] = 0;
    __syncthreads();
    int e0 = blockIdx.x * EPB, e1 = min(e0 + EPB, E);
    int isl = flagE[0];
    for (int i = e0 + tid; i < e1; i += 256) {
        int d = isl ? ei[2 * (E + i)] : ei[E + i];
        atomicAdd(&cnt[d >> 10], 1);
    }
    __syncthreads();
    for (int b = tid; b < NBC; b += 256) {
        res[b] = cnt[b] ? atomicAdd(&gcur[b], cnt[b]) : 0;
        cnt[b] = 0;                               // becomes local cursor
    }
    __syncthreads();
    for (int i = e0 + tid; i < e1; i += 256) {
        int s = isl ? ei[2 * i] : ei[i];
        int d = isl ? ei[2 * (E + i)] : ei[E + i];
        int b = d >> 10;
        int pos = res[b] + atomicAdd(&cnt[b], 1);
        bins[pos] = make_uint2((uint32_t)s, (uint32_t)d);
    }
}
__global__ __launch_bounds__(256) void csr_build(const uint2* __restrict__ bins,
                                                 const int* __restrict__ bstart,
                                                 int* __restrict__ rowptr,
                                                 int* __restrict__ csr, int M, int E) {
    int b = blockIdx.x;
    int node0 = b << 10;
    int nn = min(1024, M - node0);
    int s = bstart[b], e = bstart[b + 1];
    __shared__ int cnt[1024];
    __shared__ int ofs[1024];
    int tid = threadIdx.x;
    for (int j = tid; j < 1024; j += 256) cnt[j] = 0;
    __syncthreads();
    for (int i = s + tid; i < e; i += 256)
        atomicAdd(&cnt[bins[i].y & 1023], 1);
    __syncthreads();
    if (tid == 0) {
        int run = s;
        for (int j = 0; j < nn; ++j) { ofs[j] = run; run += cnt[j]; }
    }
    __syncthreads();
    for (int j = tid; j < nn; j += 256) rowptr[node0 + j] = ofs[j];
    if (b == 0 && tid == 0) rowptr[M] = E;
    for (int j = tid; j < 1024; j += 256) cnt[j] = 0;   // reuse as cursors
    __syncthreads();
    for (int i = s + tid; i < e; i += 256) {
        uint2 pr = bins[i];
        int d = pr.y & 1023;
        int pos = ofs[d] + atomicAdd(&cnt[d], 1);
        csr[pos] = (int)pr.x;
    }
}

// ---------- max aggregation: 4 nodes/wave (16 lanes x uint4), 8-edge unroll ----------
__global__ __launch_bounds__(256) void gather_kernel(const uint4* __restrict__ cur,
                                                     const int* __restrict__ rowptr,
                                                     const int* __restrict__ csr,
                                                     uint4* __restrict__ agg, int M) {
    int gid = blockIdx.x * 256 + threadIdx.x;
    int node = gid >> 4;
    int sl = threadIdx.x & 15;                    // 16-lane subgroup, 16 B each
    if (node >= M) return;
    int b = rowptr[node], e = rowptr[node + 1];
    float m[8];
#pragma unroll
    for (int j = 0; j < 8; ++j) m[j] = -INFINITY;
    int i = b;
    for (; i + 8 <= e; i += 8) {                  // 8 loads in flight per lane
        uint4 u[8];
#pragma unroll
        for (int t = 0; t < 8; ++t) u[t] = cur[(size_t)csr[i + t] * 16 + sl];
#pragma unroll
        for (int t = 0; t < 8; ++t) {
            uint32_t w[4] = {u[t].x, u[t].y, u[t].z, u[t].w};
#pragma unroll
            for (int j = 0; j < 4; ++j) {
                m[2 * j]     = fmaxf(m[2 * j],     bflo(w[j]));
                m[2 * j + 1] = fmaxf(m[2 * j + 1], bfhi(w[j]));
            }
        }
    }
    for (; i + 4 <= e; i += 4) {
        uint4 u[4];
#pragma unroll
        for (int t = 0; t < 4; ++t) u[t] = cur[(size_t)csr[i + t] * 16 + sl];
#pragma unroll
        for (int t = 0; t < 4; ++t) {
            uint32_t w[4] = {u[t].x, u[t].y, u[t].z, u[t].w};
#pragma unroll
            for (int j = 0; j < 4; ++j) {
                m[2 * j]     = fmaxf(m[2 * j],     bflo(w[j]));
                m[2 * j + 1] = fmaxf(m[2 * j + 1], bfhi(w[j]));
            }
        }
    }
    for (; i < e; ++i) {
        uint4 u0 = cur[(size_t)csr[i] * 16 + sl];
        uint32_t w0[4] = {u0.x, u0.y, u0.z, u0.w};
#pragma unroll
        for (int j = 0; j < 4; ++j) {
            m[2 * j]     = fmaxf(m[2 * j],     bflo(w0[j]));
            m[2 * j + 1] = fmaxf(m[2 * j + 1], bfhi(w0[j]));
        }
    }
    if (b == e) {
#pragma unroll
        for (int j = 0; j < 8; ++j) m[j] = 0.f;   // no neighbors -> 0 (isfinite rule)
    }
    uint4 o;
    o.x = pack2(m[0], m[1]); o.y = pack2(m[2], m[3]);
    o.z = pack2(m[4], m[5]); o.w = pack2(m[6], m[7]);
    agg[(size_t)node * 16 + sl] = o;
}

// ---------- MFMA GEMM: out[M][N] = sum_s A_s @ W_s^T + bias ----------
// X staged via LDS (r8-proven geometry). W read DIRECTLY from global in the
// K-loop: W is <=64 KB total, L1/L2-resident after chunk 0 — LDS staging of W
// bought nothing and cost 18 KB LDS + 16 prefetch VGPRs + barrier-guarded
// writes. (256,4): with LW/rw gone, est. VGPR ~122 <= 128 cap -> 4 blocks/CU.
// Spill check next round: WRITE_SIZE >> 27 MB means spilled (r10 signature).
// NOTE: BN-stats fusion attempted twice (r6 atomics, r10 spill) — regressed.
template<int N, int NSRC, bool FC2>
__global__ __launch_bounds__(256, 4) void gemm_mfma(
    const uint16_t* __restrict__ A0, const uint16_t* __restrict__ W0,
    const uint16_t* __restrict__ A1, const uint16_t* __restrict__ W1,
    const float* __restrict__ bias, void* __restrict__ out_, int M,
    const float* __restrict__ fc2w)
{
    constexpr int LDT = 72;                       // row stride in uint16 (144 B)
    constexpr int WAVES_N = N / 64;               // 2 (N=128) or 1 (N=64)
    constexpr int WAVES_M = 4 / WAVES_N;          // 2 or 4
    constexpr int MT = 8 / WAVES_M;               // m-tiles/wave: 4 or 2
    constexpr int NT = 4;                         // n-tiles/wave (64 cols)
    constexpr int CHUNKS = 2 * NSRC;              // BK=64 chunks
    __shared__ uint16_t LX[128 * LDT];            // X tile [row][k64]
    const int tid = threadIdx.x;
    const int wave = tid >> 6, lane = tid & 63;
    const int l15 = lane & 15, lkg = lane >> 4;   // k-group 0..3
    const int wn = (wave % WAVES_N) * 64;
    const int wm = (wave / WAVES_N) * (128 / WAVES_M);
    const int row0 = blockIdx.x * 128;
    const int srow = tid >> 3;                    // staging row 0..31 (+32*pass)
    const int sko = (tid & 7) * 8;                // staging k offset, uint16 units

    f32x4 acc[NT][MT];
#pragma unroll
    for (int nt = 0; nt < NT; ++nt)
#pragma unroll
        for (int mt = 0; mt < MT; ++mt) {
            f32x4 z4 = {0.f, 0.f, 0.f, 0.f};
            acc[nt][mt] = z4;
        }

    const uint16_t* Asrc[2] = {A0, NSRC > 1 ? A1 : A0};
    const uint16_t* Wsrc[2] = {W0, NSRC > 1 ? W1 : W0};

    uint4 rx[4];
    // prefetch chunk 0 (src 0, kc 0)
#pragma unroll
    for (int it = 0; it < 4; ++it) {
        int gr = row0 + srow + it * 32;
        uint4 v = make_uint4(0, 0, 0, 0);
        if (gr < M) v = *(const uint4*)(Asrc[0] + (size_t)gr * HID + sko);
        rx[it] = v;
    }

#pragma unroll 1
    for (int c = 0; c < CHUNKS; ++c) {
        const int csrc = c >> 1, ckc = c & 1;     // current chunk's source / k-half
        const uint16_t* Wg = Wsrc[csrc];
        __syncthreads();
#pragma unroll
        for (int it = 0; it < 4; ++it)
            *(uint4*)&LX[(srow + it * 32) * LDT + sko] = rx[it];
        __syncthreads();
        if (c + 1 < CHUNKS) {                     // issue next chunk's X loads now
            int nc = c + 1, src = nc >> 1, kc = nc & 1;
            const uint16_t* Ag = Asrc[src];
#pragma unroll
            for (int it = 0; it < 4; ++it) {
                int gr = row0 + srow + it * 32;
                uint4 v = make_uint4(0, 0, 0, 0);
                if (gr < M) v = *(const uint4*)(Ag + (size_t)gr * HID + kc * 64 + sko);
                rx[it] = v;
            }
        }
#pragma unroll
        for (int ks = 0; ks < 2; ++ks) {
            bf16x8 xf[MT], wf[NT];
#pragma unroll
            for (int mt = 0; mt < MT; ++mt)
                xf[mt] = ldfrag(&LX[(wm + mt * 16 + l15) * LDT + ks * 32 + lkg * 8]);
#pragma unroll
            for (int nt = 0; nt < NT; ++nt)       // W direct from global (L1-hot)
                wf[nt] = ldfrag(Wg + (size_t)(wn + nt * 16 + l15) * HID +
                                ckc * 64 + ks * 32 + lkg * 8);
#pragma unroll
            for (int nt = 0; nt < NT; ++nt)
#pragma unroll
                for (int mt = 0; mt < MT; ++mt)
                    acc[nt][mt] = __builtin_amdgcn_mfma_f32_16x16x32_bf16(
                        wf[nt], xf[mt], acc[nt][mt], 0, 0, 0);
        }
    }

    if constexpr (FC2) {
        float rowdot[MT];
#pragma unroll
        for (int mt = 0; mt < MT; ++mt) rowdot[mt] = 0.f;
#pragma unroll
        for (int nt = 0; nt < NT; ++nt) {
            int n0 = wn + nt * 16 + lkg * 4;
            float b4[4] = {bias[n0], bias[n0 + 1], bias[n0 + 2], bias[n0 + 3]};
            float w4[4] = {fc2w[n0], fc2w[n0 + 1], fc2w[n0 + 2], fc2w[n0 + 3]};
#pragma unroll
            for (int mt = 0; mt < MT; ++mt) {
                f32x4 f = acc[nt][mt];
#pragma unroll
                for (int j = 0; j < 4; ++j)
                    rowdot[mt] = fmaf(lrelu_f(f[j] + b4[j]), w4[j], rowdot[mt]);
            }
        }
        float b2 = fc2w[64];
#pragma unroll
        for (int mt = 0; mt < MT; ++mt) {
            float v = rowdot[mt];
            v += __shfl_xor(v, 16, 64);
            v += __shfl_xor(v, 32, 64);
            int m = row0 + wm + mt * 16 + l15;
            if (lkg == 0 && m < M) ((float*)out_)[m] = v + b2;
        }
    } else {
#pragma unroll
        for (int nt = 0; nt < NT; ++nt) {
            int n0 = wn + nt * 16 + lkg * 4;
            float b0 = bias[n0], b1 = bias[n0 + 1], b2 = bias[n0 + 2], b3 = bias[n0 + 3];
#pragma unroll
            for (int mt = 0; mt < MT; ++mt) {
                int m = row0 + wm + mt * 16 + l15;
                if (m < M) {
                    f32x4 f = acc[nt][mt];
                    ushort4 ov;
                    ov.x = f2bf(f[0] + b0); ov.y = f2bf(f[1] + b1);
                    ov.z = f2bf(f[2] + b2); ov.w = f2bf(f[3] + b3);
                    *(ushort4*)((uint16_t*)out_ + (size_t)m * N + n0) = ov;
                }
            }
        }
    }
}

// ---------- batch norm (stats kernel r5-proven; finalize folded into apply) ----------
__global__ __launch_bounds__(256) void bn_stats(const uint32_t* __restrict__ z,
                                                float* __restrict__ stats, int M, int rpb) {
    __shared__ float4 red[256];
    int c2 = threadIdx.x & 63;                    // uint32 column (2 features)
    int part = threadIdx.x >> 6;                  // 0..3
    int s0 = blockIdx.x * rpb, e0 = min(s0 + rpb, M);
    float sl = 0.f, s2l = 0.f, sh = 0.f, s2h = 0.f;
    for (int r = s0 + part; r < e0; r += 4) {
        uint32_t u = z[(size_t)r * 64 + c2];
        float a = bflo(u), b = bfhi(u);
        sl += a; s2l = fmaf(a, a, s2l);
        sh += b; s2h = fmaf(b, b, s2h);
    }
    red[threadIdx.x] = make_float4(sl, s2l, sh, s2h);
    __syncthreads();
    if (threadIdx.x < 64) {
        float4 v = red[threadIdx.x];
        float4 v1 = red[threadIdx.x + 64], v2 = red[threadIdx.x + 128], v3 = red[threadIdx.x + 192];
        v.x += v1.x + v2.x + v3.x; v.y += v1.y + v2.y + v3.y;
        v.z += v1.z + v2.z + v3.z; v.w += v1.w + v2.w + v3.w;
        int cc = c2 * 2;
        atomicAdd(&stats[cc], v.x);
        atomicAdd(&stats[128 + cc], v.y);
        atomicAdd(&stats[cc + 1], v.z);
        atomicAdd(&stats[129 + cc], v.w);
    }
}
__device__ __forceinline__ float2 bn_coeff(const float* stats, const float* g,
                                           const float* be, int c, float invM) {
    float mean = stats[c] * invM;
    float var = stats[128 + c] * invM - mean * mean;
    float sc = g[c] * rsqrtf(var + 1e-5f);
    return make_float2(sc, be[c] - mean * sc);
}
__global__ __launch_bounds__(256) void bn_apply(uint32_t* __restrict__ z,
                                                const float* __restrict__ stats,
                                                const float* __restrict__ g,
                                                const float* __restrict__ be,
                                                int M, int total2) {
    int i = blockIdx.x * 256 + threadIdx.x;
    if (i >= total2) return;
    float invM = 1.f / (float)M;
    int cc = (i & 63) * 2;
    float2 k0 = bn_coeff(stats, g, be, cc, invM);
    float2 k1 = bn_coeff(stats, g, be, cc + 1, invM);
    uint32_t u = z[i];
    float a = lrelu_f(fmaf(bflo(u), k0.x, k0.y));
    float b = lrelu_f(fmaf(bfhi(u), k1.x, k1.y));
    z[i] = pack2(a, b);
}
// layer-3 variant with fused residual add: z = lrelu(bn(z)) + h0
__global__ __launch_bounds__(256) void bn_apply_res(uint32_t* __restrict__ z,
                                                    const uint32_t* __restrict__ h0,
                                                    const float* __restrict__ stats,
                                                    const float* __restrict__ g,
                                                    const float* __restrict__ be,
                                                    int M, int total2) {
    int i = blockIdx.x * 256 + threadIdx.x;
    if (i >= total2) return;
    float invM = 1.f / (float)M;
    int cc = (i & 63) * 2;
    float2 k0 = bn_coeff(stats, g, be, cc, invM);
    float2 k1 = bn_coeff(stats, g, be, cc + 1, invM);
    uint32_t u = z[i], r = h0[i];
    float a = lrelu_f(fmaf(bflo(u), k0.x, k0.y)) + bflo(r);
    float b = lrelu_f(fmaf(bfhi(u), k1.x, k1.y)) + bfhi(r);
    z[i] = pack2(a, b);
}

// ---------- launch ----------
extern "C" void kernel_launch(void* const* d_in, const int* in_sizes, int n_in,
                              void* d_out, int out_size, void* d_ws, size_t ws_size,
                              hipStream_t stream) {
    const void* x = d_in[0];                               // [M][128] bf16 or fp32
    const int* ei = (const int*)d_in[1];                   // int32 or int64 [2][E]
    const int M = in_sizes[0] / HID;                       // 100000
    const int E = in_sizes[1] / 2;                         // 1600000
    const int NBC = (M + 1023) >> 10;                      // 1024-node buckets (<=1024)
    const int gemm_grid = (M + 127) / 128;

    // workspace layout — ~84 MB (P doubles as 12.8 MB bin scratch pre-layer1)
    const size_t FEAT = (size_t)M * HID * 2;               // 25.6 MB per bf16 buffer
    char* p = (char*)d_ws;
    uint16_t* H0 = (uint16_t*)p; p += FEAT;                // residual, persists
    uint16_t* P  = (uint16_t*)p; p += FEAT;                // ALSO: edge bins (uint2[E])
    uint16_t* Q  = (uint16_t*)p; p += FEAT;
    uint16_t* WT = (uint16_t*)p; p += 8 * 16384 * 2;       // 8 bf16 weight slots [n][k]
    float* params = (float*)p; p += 8192;                  // canonical fp32 params
    int* rowptr  = (int*)p; p += ((size_t)M + 32) * 4;
    int* csr     = (int*)p; p += (size_t)E * 4;
    int* bcnt    = (int*)p; p += 1024 * 4;                 // coarse bucket counts
    int* bstart  = (int*)p; p += 1056 * 4;                 // bucket region bases
    int* gcur    = (int*)p; p += 1024 * 4;                 // bucket fill cursors
    float* stats = (float*)p; p += 3 * 256 * 4;            // 3 BN raw-sum slots
    int* flagE   = (int*)p; p += 128;
    int* flagF   = (int*)p; p += 128;

    const size_t needed = (size_t)(p - (char*)d_ws);
    if (needed > ws_size) {                                // diagnostic sentinel
        sentinel_kernel<<<(out_size + 255) / 256, 256, 0, stream>>>(
            (float*)d_out, out_size);
        return;
    }

    uint16_t* wt[8];
    for (int i = 0; i < 8; ++i) wt[i] = WT + (size_t)i * 16384;

    // 0) dtype probes
    detect_e_kernel<<<1, 64, 0, stream>>>(ei, flagE);
    detect_f_kernel<<<1, 64, 0, stream>>>((const uint32_t*)x, flagF);

    // 1) canonicalize weights + params + x
    WArgs wa;
    const int widx[8] = {2, 4, 6, 7, 9, 10, 12, 19};       // W_in,Wl1,Wr1,Wl2,Wr2,Wl3,Wr3,Wfc1
    for (int i = 0; i < 8; ++i) {
        wa.src[i] = d_in[widx[i]];
        wa.dst[i] = wt[i];
        wa.nrows[i] = (i == 7) ? 64 : 128;
    }
    convert_w<<<512, 256, 0, stream>>>(wa, flagF);

    ParamArgs pa;
    const int pidx[14] = {3, 5, 8, 11, 13, 15, 17, 14, 16, 18, 20, 21, 22, 22};
    const int poff[14] = {0, 128, 256, 384, 512, 640, 768, 896, 1024, 1152, 1280, 1344, 1408, 1409};
    const int pcnt[14] = {128, 128, 128, 128, 128, 128, 128, 128, 128, 128, 64, 64, 1, 0};
    for (int i = 0; i < 14; ++i) { pa.src[i] = d_in[pidx[i]]; pa.off[i] = poff[i]; pa.cnt[i] = pcnt[i]; }
    convert_params<<<14, 128, 0, stream>>>(pa, params, flagF);
    // map: 0 b_in | 128/256/384 b_l1..3 | 512/640/768 g1..3 | 896/1024/1152 be1..3
    //      1280 b_fc1[64] | 1344 W_fc2[64] | 1408 b_fc2

    const int total2 = M * (HID / 2);
    const int ew_grid = (total2 + 255) / 256;
    convert_x<<<ew_grid, 256, 0, stream>>>(x, (uint32_t*)Q, flagF, total2);

    // 2) CSR build: coarse hist -> scan -> block-local binned fill -> per-bucket CSR
    hipMemsetAsync(bcnt, 0, 1024 * sizeof(int), stream);
    hipMemsetAsync(stats, 0, 3 * 256 * sizeof(float), stream);
    const int fgrid = (E + EPB - 1) / EPB;
    bucket_hist<<<fgrid, 256, 0, stream>>>(ei, flagE, bcnt, E, NBC);
    bucket_scan<<<1, 1024, 0, stream>>>(bcnt, bstart, gcur, NBC, E);
    bucket_fill<<<fgrid, 256, 0, stream>>>(ei, flagE, gcur, (uint2*)P, E, NBC);
    csr_build<<<NBC, 256, 0, stream>>>((const uint2*)P, bstart, rowptr, csr, M, E);

    const int gather_grid = (M + 15) / 16;                 // 4 nodes per wave
    const int rpb = (M + 255) / 256;

    // 3) h0 = x @ W_in^T + b_in  (residual, bf16)
    gemm_mfma<128, 1, false><<<gemm_grid, 256, 0, stream>>>(
        Q, wt[0], nullptr, nullptr, params + 0, H0, M, nullptr);

    // 4) three SAGE layers (gather -> gemm in-place -> bn_stats -> apply w/ inline finalize)
    uint16_t* wtl[3] = {wt[1], wt[3], wt[5]};
    uint16_t* wtr[3] = {wt[2], wt[4], wt[6]};
    uint16_t* cur = H0;
    uint16_t* dstb[3] = {P, Q, P};
    for (int l = 0; l < 3; ++l) {
        uint16_t* z = dstb[l];
        float* sl = stats + 256 * l;
        const float* gg = params + 512 + l * 128;
        const float* bb = params + 896 + l * 128;
        gather_kernel<<<gather_grid, 256, 0, stream>>>(
            (const uint4*)cur, rowptr, csr, (uint4*)z, M);
        gemm_mfma<128, 2, false><<<gemm_grid, 256, 0, stream>>>(
            z, wtl[l], cur, wtr[l], params + 128 + l * 128, z, M, nullptr);
        bn_stats<<<256, 256, 0, stream>>>((const uint32_t*)z, sl, M, rpb);
        if (l < 2)
            bn_apply<<<ew_grid, 256, 0, stream>>>((uint32_t*)z, sl, gg, bb, M, total2);
        else
            bn_apply_res<<<ew_grid, 256, 0, stream>>>((uint32_t*)z, (const uint32_t*)H0,
                                                      sl, gg, bb, M, total2);
        cur = z;
    }

    // 5) fused fc1(+lrelu)+fc2 -> fp32 d_out
    gemm_mfma<64, 1, true><<<gemm_grid, 256, 0, stream>>>(
        P, wt[7], nullptr, nullptr, params + 1280, (float*)d_out, M, params + 1344);
}